// Round 5
// baseline (308.157 us; speedup 1.0000x reference)
//
#include <hip/hip_runtime.h>
#include <stdint.h>

#define M_DIM 8192
#define N_DIM 4096
#define K_DIM 4096
#define NBLK  (K_DIM / 32)

typedef __attribute__((ext_vector_type(4))) float          f32x4;
typedef __attribute__((ext_vector_type(8))) short          bf16x8;
typedef __attribute__((ext_vector_type(4))) int            i32x4;
typedef __attribute__((ext_vector_type(8))) unsigned short u16x8;
typedef __attribute__((address_space(3))) unsigned short   lds_us;

// round-to-nearest-even fp32 -> bf16 bits (finite values only)
__device__ __forceinline__ unsigned short f2bf(float f) {
  unsigned u = __builtin_bit_cast(unsigned, f);
  u += 0x7fffu + ((u >> 16) & 1u);
  return (unsigned short)(u >> 16);
}

__device__ __forceinline__ void stage16(const unsigned short* g, lds_us* l) {
  __builtin_amdgcn_global_load_lds(
      (const __attribute__((address_space(1))) void*)g,
      (__attribute__((address_space(3))) void*)l, 16, 0, 0);
}

// inline-asm ds_read_b128 with immediate byte offset
template <int OFF>
__device__ __forceinline__ bf16x8 dsr(lds_us* addr) {
  bf16x8 d;
  asm volatile("ds_read_b128 %0, %1 offset:%2" : "=v"(d) : "v"(addr), "n"(OFF));
  return d;
}

// ============ BLOCKED GLOBAL LAYOUT for xb / wb ============
// Element (row, k) lives at granule G = ((g*NH + H)*16 + R*2 + Kt)*64 + c*16 + r
// where g=k/64, Kt=(k%64)/32, c=(k%32)/8, e=k%8, H=row/128, R=(row%128)/16,
// r=row%16; flat elem = G*8 + e.  One granule = 8 elems = 16 B (one MFMA frag
// slice).  A (row-half, K-tile) pair occupies a contiguous 16-KB block, and
// within a 1-KB subtile, granule slot index == MFMA lane — so GEMM staging is
// an identity copy (1 KB contiguous per wave) and ds_reads are conflict-free.

// ---------------- dequant: wq int32 [N,K] row-major -> wb blocked bf16
__global__ void MXFP4_dequant_kernel(const int* __restrict__ wq,
                                     const float* __restrict__ scales,
                                     unsigned short* __restrict__ wb) {
  size_t t = (size_t)blockIdx.x * 256 + threadIdx.x;   // granule id, < 2^21
  int slot = (int)(t & 63);
  int r = slot & 15, c = slot >> 4;
  int sub = (int)(t >> 6) & 15;
  int R = sub >> 1, Kt = sub & 1;
  int H = (int)(t >> 10) & 31;
  int g = (int)(t >> 15);
  size_t row = (size_t)H * 128 + R * 16 + r;
  size_t k   = (size_t)g * 64 + Kt * 32 + c * 8;
  float s = scales[row * NBLK + (g * 2 + Kt)] * (1.0f / 7.0f);
  const int* src = wq + row * K_DIM + k;
  i32x4 q0 = *(const i32x4*)src;
  i32x4 q1 = *(const i32x4*)(src + 4);
  u16x8 out;
#pragma unroll
  for (int j = 0; j < 4; ++j) out[j]     = f2bf((float)q0[j] * s);
#pragma unroll
  for (int j = 0; j < 4; ++j) out[4 + j] = f2bf((float)q1[j] * s);
  *(u16x8*)(wb + t * 8) = out;
}

// ---------------- x fp32 [M,K] row-major -> xb blocked bf16
__global__ void MXFP4_cvt_kernel(const float* __restrict__ x,
                                 unsigned short* __restrict__ xb) {
  size_t t = (size_t)blockIdx.x * 256 + threadIdx.x;   // granule id, < 2^22
  int slot = (int)(t & 63);
  int r = slot & 15, c = slot >> 4;
  int sub = (int)(t >> 6) & 15;
  int R = sub >> 1, Kt = sub & 1;
  int H = (int)(t >> 10) & 63;
  int g = (int)(t >> 16);
  size_t row = (size_t)H * 128 + R * 16 + r;
  size_t k   = (size_t)g * 64 + Kt * 32 + c * 8;
  const float* src = x + row * K_DIM + k;
  f32x4 v0 = *(const f32x4*)src;
  f32x4 v1 = *(const f32x4*)(src + 4);
  u16x8 out;
#pragma unroll
  for (int j = 0; j < 4; ++j) out[j]     = f2bf(v0[j]);
#pragma unroll
  for (int j = 0; j < 4; ++j) out[4 + j] = f2bf(v1[j]);
  *(u16x8*)(xb + t * 8) = out;
}

// ---------------- GEMM: A,B pre-blocked bf16, C [M,N] f32 + bias
// 256x256 tile, BK=64, 8 waves (2Mx4N), **2 phases per K-tile with 32-MFMA
// clusters** (AITER-style density), counted vmcnt(4), identity-copy staging,
// zero bank conflicts.
// LDS elems: A buf b at b*16384; B buf b at 32768+b*16384; dummy at 65536.

#define BAR() __builtin_amdgcn_s_barrier()
#define WAIT_LGKM0() do { asm volatile("s_waitcnt lgkmcnt(0)" ::: "memory"); \
                          __builtin_amdgcn_sched_barrier(0); } while (0)

#define ST_A(t_, h_, BUFA_, valid_) do { \
  if (valid_) { \
    const unsigned short* s_ = Abase + ((size_t)(t_) * 64 + (h_)) * 8192 + tid8; \
    lds_us* d_ = lp + (BUFA_) * 16384 + (h_) * 8192 + tid8; \
    stage16(s_, d_); stage16(s_ + 4096, d_ + 4096); \
  } else { stage16(Abase + tid8, lp + 65536); \
           stage16(Abase + tid8 + 4096, lp + 65536 + 512); } \
} while (0)

#define ST_B(t_, h_, BUFB_, valid_) do { \
  if (valid_) { \
    const unsigned short* s_ = Bbase + ((size_t)(t_) * 32 + (h_)) * 8192 + tid8; \
    lds_us* d_ = lp + 32768 + (BUFB_) * 16384 + (h_) * 8192 + tid8; \
    stage16(s_, d_); stage16(s_ + 4096, d_ + 4096); \
  } else { stage16(Bbase + tid8, lp + 65536); \
           stage16(Bbase + tid8 + 4096, lp + 65536 + 512); } \
} while (0)

#define MF(MB_, NB_, AF_, BF_) do { \
  _Pragma("unroll") \
  for (int kk_ = 0; kk_ < 2; ++kk_) \
    _Pragma("unroll") \
    for (int mm_ = 0; mm_ < 4; ++mm_) \
      _Pragma("unroll") \
      for (int nn_ = 0; nn_ < 2; ++nn_) \
        acc[(MB_) + mm_][(NB_) + nn_] = __builtin_amdgcn_mfma_f32_16x16x32_bf16( \
            AF_[mm_][kk_], BF_[nn_][kk_], acc[(MB_) + mm_][(NB_) + nn_], 0, 0, 0); \
} while (0)

// One 2-phase group computing K-tile g from buffer BUF_ (= g&1).
// Phase A: read aLo,aHi,bLo (20 ds_read_b128) + stage B(tB_) h0,h1 into BUF_^1
//          -> 32 MFMA (n-quadrants 0-1).
// Phase B: read bHi (4) + stage A(tA_) h0,h1 into BUF_; vmcnt(4) publishes
//          tile g+1 (A(g+2)'s 4 loads stay in flight) -> 32 MFMA (n 2-3).
// Hazards: A-region restage (phase B) happens after phase A's barrier+lgkm0,
// where every wave's A reads (aLo+aHi, drained) completed. B^1-region restage
// (phase A) is after the previous K-tile's full drain. DMA lands under vmcnt.
#define GROUP(BUF_, tB_, tA_, vB_, vA_) do { \
  lds_us* dsA_ = lp + (BUF_) * 16384 + wm * 8192 + lane * 8; \
  lds_us* dsB_ = lp + 32768 + (BUF_) * 16384 + wn * 4096 + lane * 8; \
  /* ---- phase A: Q00+Q10 (m0-7, n0-1) ---- */ \
  aLo[0][0] = dsr<0>(dsA_);      aLo[0][1] = dsr<1024>(dsA_); \
  aLo[1][0] = dsr<2048>(dsA_);   aLo[1][1] = dsr<3072>(dsA_); \
  aLo[2][0] = dsr<4096>(dsA_);   aLo[2][1] = dsr<5120>(dsA_); \
  aLo[3][0] = dsr<6144>(dsA_);   aLo[3][1] = dsr<7168>(dsA_); \
  aHi[0][0] = dsr<8192>(dsA_);   aHi[0][1] = dsr<9216>(dsA_); \
  aHi[1][0] = dsr<10240>(dsA_);  aHi[1][1] = dsr<11264>(dsA_); \
  aHi[2][0] = dsr<12288>(dsA_);  aHi[2][1] = dsr<13312>(dsA_); \
  aHi[3][0] = dsr<14336>(dsA_);  aHi[3][1] = dsr<15360>(dsA_); \
  bLo[0][0] = dsr<0>(dsB_);      bLo[0][1] = dsr<1024>(dsB_); \
  bLo[1][0] = dsr<2048>(dsB_);   bLo[1][1] = dsr<3072>(dsB_); \
  ST_B(tB_, 0, (BUF_) ^ 1, vB_); \
  ST_B(tB_, 1, (BUF_) ^ 1, vB_); \
  BAR(); WAIT_LGKM0(); \
  __builtin_amdgcn_s_setprio(1); \
  MF(0, 0, aLo, bLo); \
  MF(4, 0, aHi, bLo); \
  __builtin_amdgcn_s_setprio(0); \
  BAR(); \
  /* ---- phase B: Q01+Q11 (m0-7, n2-3) ---- */ \
  bHi[0][0] = dsr<4096>(dsB_);   bHi[0][1] = dsr<5120>(dsB_); \
  bHi[1][0] = dsr<6144>(dsB_);   bHi[1][1] = dsr<7168>(dsB_); \
  ST_A(tA_, 0, (BUF_), vA_); \
  ST_A(tA_, 1, (BUF_), vA_); \
  asm volatile("s_waitcnt vmcnt(4)" ::: "memory"); \
  BAR(); WAIT_LGKM0(); \
  __builtin_amdgcn_s_setprio(1); \
  MF(0, 2, aLo, bHi); \
  MF(4, 2, aHi, bHi); \
  __builtin_amdgcn_s_setprio(0); \
  BAR(); \
} while (0)

__global__ __launch_bounds__(512, 2) void MXFP4_gemm_kernel(
    const unsigned short* __restrict__ A,
    const unsigned short* __restrict__ B,
    const float* __restrict__ bias,
    float* __restrict__ C) {
  __shared__ unsigned short LDS[66560];  // 130 KB
  lds_us* lp = (lds_us*)LDS;

  const int tid  = threadIdx.x;
  const int lane = tid & 63;
  const int wv   = tid >> 6;   // wave 0..7
  const int wm   = wv >> 2;    // 0..1  (M half)
  const int wn   = wv & 3;     // 0..3  (N quarter)
  const int tid8 = tid * 8;

  // 2-D chunk XCD swizzle: XCD x owns an 8tm x 8tn sub-square (bijective).
  const int bid = blockIdx.x;
  const int xcd = bid & 7;
  const int idx = bid >> 3;                 // 0..63 within XCD
  const int tm  = (xcd & 3) * 8 + (idx & 7);   // 0..31
  const int tn  = (xcd >> 2) * 8 + (idx >> 3); // 0..15
  const int brow = tm * 256;
  const int bcol = tn * 256;

  // blocked-layout staging bases (identity copy: 16-KB block per (tile, half))
  const unsigned short* Abase = A + (size_t)(tm * 2) * 8192;
  const unsigned short* Bbase = B + (size_t)(tn * 2) * 8192;

  f32x4 acc[8][4] = {};
  bf16x8 aLo[4][2], aHi[4][2], bLo[2][2], bHi[2][2];

  // ---- prologue: tile 0 (A lo/hi, B lo/hi) + tile 1 A halves ----
  ST_A(0, 0, 0, true); ST_A(0, 1, 0, true);
  ST_B(0, 0, 0, true); ST_B(0, 1, 0, true);
  ST_A(1, 0, 1, true); ST_A(1, 1, 1, true);
  asm volatile("s_waitcnt vmcnt(4)" ::: "memory");  // tile 0 landed; A(1) in flight
  BAR();

  // ---- main loop: 31 iters x 2 K-tiles ----
  for (int it = 0; it < 31; ++it) {
    const int g0 = 2 * it;
    GROUP(0, g0 + 1, g0 + 2, true, true);
    GROUP(1, g0 + 2, g0 + 3, true, true);
  }
  // ---- tail groups 62, 63 (dummy stages keep vmcnt accounting uniform) ----
  GROUP(0, 63, 64, true, false);
  GROUP(1, 64, 65, false, false);

  // ---- epilogue: C = acc + bias;  frag: col=lane&15, row=(lane>>4)*4+j ----
  const int rb = brow + wm * 128 + (lane >> 4) * 4;
  const int cb = bcol + wn * 64 + (lane & 15);
#pragma unroll
  for (int n = 0; n < 4; ++n) {
    const int col = cb + n * 16;
    const float bv = bias[col];
#pragma unroll
    for (int m = 0; m < 8; ++m) {
      const int row = rb + m * 16;
#pragma unroll
      for (int j = 0; j < 4; ++j)
        C[(size_t)(row + j) * N_DIM + col] = acc[m][n][j] + bv;
    }
  }
}

extern "C" void kernel_launch(void* const* d_in, const int* in_sizes, int n_in,
                              void* d_out, int out_size, void* d_ws, size_t ws_size,
                              hipStream_t stream) {
  const float* x      = (const float*)d_in[0];
  const int*   wq     = (const int*)d_in[1];
  const float* scales = (const float*)d_in[2];
  const float* bias   = (const float*)d_in[3];
  float*       out    = (float*)d_out;

  unsigned short* wb = (unsigned short*)d_ws;                    // 33.5 MB blocked
  unsigned short* xb = wb + (size_t)N_DIM * K_DIM;               // 67 MB blocked

  MXFP4_dequant_kernel<<<(N_DIM * (long)K_DIM / 8) / 256, 256, 0, stream>>>(wq, scales, wb);
  MXFP4_cvt_kernel<<<(M_DIM * (long)K_DIM / 8) / 256, 256, 0, stream>>>(x, xb);

  MXFP4_gemm_kernel<<<512, 512, 0, stream>>>(xb, wb, bias, out);
}

// Round 6
// 305.047 us; speedup vs baseline: 1.0102x; 1.0102x over previous
//
#include <hip/hip_runtime.h>
#include <stdint.h>

#define M_DIM 8192
#define N_DIM 4096
#define K_DIM 4096
#define NBLK  (K_DIM / 32)

typedef __attribute__((ext_vector_type(4))) float          f32x4;
typedef __attribute__((ext_vector_type(8))) short          bf16x8;
typedef __attribute__((ext_vector_type(4))) int            i32x4;
typedef __attribute__((ext_vector_type(8))) unsigned short u16x8;
typedef __attribute__((address_space(3))) unsigned short   lds_us;

// round-to-nearest-even fp32 -> bf16 bits (finite values only)
__device__ __forceinline__ unsigned short f2bf(float f) {
  unsigned u = __builtin_bit_cast(unsigned, f);
  u += 0x7fffu + ((u >> 16) & 1u);
  return (unsigned short)(u >> 16);
}

__device__ __forceinline__ void stage16(const unsigned short* g, lds_us* l) {
  __builtin_amdgcn_global_load_lds(
      (const __attribute__((address_space(1))) void*)g,
      (__attribute__((address_space(3))) void*)l, 16, 0, 0);
}

// inline-asm ds_read_b128 with immediate byte offset
template <int OFF>
__device__ __forceinline__ bf16x8 dsr(lds_us* addr) {
  bf16x8 d;
  asm volatile("ds_read_b128 %0, %1 offset:%2" : "=v"(d) : "v"(addr), "n"(OFF));
  return d;
}

// ============ BLOCKED GLOBAL LAYOUT for xb / wb ============
// Element (row, k) lives at granule G = ((g*NH + H)*16 + R*2 + Kt)*64 + c*16 + r
// where g=k/64, Kt=(k%64)/32, c=(k%32)/8, e=k%8, H=row/128, R=(row%128)/16,
// r=row%16; flat elem = G*8 + e.  One granule = 8 elems = 16 B (one MFMA frag
// slice).  A (row-half, K-tile) pair occupies a contiguous 16-KB block, and
// within a 1-KB subtile, granule slot index == MFMA lane — so GEMM staging is
// an identity copy (1 KB contiguous per wave) and ds_reads are conflict-free.

// ---------------- dequant: wq int32 [N,K] row-major -> wb blocked bf16
__global__ void MXFP4_dequant_kernel(const int* __restrict__ wq,
                                     const float* __restrict__ scales,
                                     unsigned short* __restrict__ wb) {
  size_t t = (size_t)blockIdx.x * 256 + threadIdx.x;   // granule id
  int slot = (int)(t & 63);
  int r = slot & 15, c = slot >> 4;
  int sub = (int)(t >> 6) & 15;
  int R = sub >> 1, Kt = sub & 1;
  int H = (int)(t >> 10) & 31;
  int g = (int)(t >> 15);
  size_t row = (size_t)H * 128 + R * 16 + r;
  size_t k   = (size_t)g * 64 + Kt * 32 + c * 8;
  float s = scales[row * NBLK + (g * 2 + Kt)] * (1.0f / 7.0f);
  const int* src = wq + row * K_DIM + k;
  i32x4 q0 = *(const i32x4*)src;
  i32x4 q1 = *(const i32x4*)(src + 4);
  u16x8 out;
#pragma unroll
  for (int j = 0; j < 4; ++j) out[j]     = f2bf((float)q0[j] * s);
#pragma unroll
  for (int j = 0; j < 4; ++j) out[4 + j] = f2bf((float)q1[j] * s);
  *(u16x8*)(wb + t * 8) = out;
}

// ---------------- x fp32 [M,K] row-major -> xb blocked bf16
__global__ void MXFP4_cvt_kernel(const float* __restrict__ x,
                                 unsigned short* __restrict__ xb) {
  size_t t = (size_t)blockIdx.x * 256 + threadIdx.x;   // granule id
  int slot = (int)(t & 63);
  int r = slot & 15, c = slot >> 4;
  int sub = (int)(t >> 6) & 15;
  int R = sub >> 1, Kt = sub & 1;
  int H = (int)(t >> 10) & 63;
  int g = (int)(t >> 16);
  size_t row = (size_t)H * 128 + R * 16 + r;
  size_t k   = (size_t)g * 64 + Kt * 32 + c * 8;
  const float* src = x + row * K_DIM + k;
  f32x4 v0 = *(const f32x4*)src;
  f32x4 v1 = *(const f32x4*)(src + 4);
  u16x8 out;
#pragma unroll
  for (int j = 0; j < 4; ++j) out[j]     = f2bf(v0[j]);
#pragma unroll
  for (int j = 0; j < 4; ++j) out[4 + j] = f2bf(v1[j]);
  *(u16x8*)(xb + t * 8) = out;
}

// ---------------- GEMM: A,B pre-blocked bf16, C [M,N] f32 + bias
// 256x256 tile, BK=64, 8 waves (2Mx4N), 4 phases/K-tile with ROTATED ds_reads:
// each read batch is issued one phase early and drained with counted lgkmcnt,
// so the LDS pipe works under the MFMA clusters instead of serializing.
//   ph4(g-1): issue aLo,bLo(g)          || MF Q11(g-1)
//   ph1(g):   issue aHi(g); lgkm(8)  -> MF Q00  || aHi completing
//   ph2(g):   issue bHi(g); lgkm(4)  -> MF Q10  || bHi completing
//   ph3(g):   lgkm(0)                -> MF Q01
//   ph4(g):   vmcnt(4); issue aLo,bLo(g+1) -> MF Q11
// Staging (identity copy): ph1/ph2 B(g+1)->BUF^1, ph3/ph4 A(g+2)->BUF.
// LDS elems: A buf b at b*16384; B buf b at 32768+b*16384; dummy at 65536.

#define BAR() __builtin_amdgcn_s_barrier()
#define WAIT_LGKM(N_) do { asm volatile("s_waitcnt lgkmcnt(%0)" :: "n"(N_) : "memory"); \
                           __builtin_amdgcn_sched_barrier(0); } while (0)

#define ST_A(t_, h_, BUFA_, valid_) do { \
  if (valid_) { \
    const unsigned short* s_ = Abase + ((size_t)(t_) * 64 + (h_)) * 8192 + tid8; \
    lds_us* d_ = lp + (BUFA_) * 16384 + (h_) * 8192 + tid8; \
    stage16(s_, d_); stage16(s_ + 4096, d_ + 4096); \
  } else { stage16(Abase + tid8, lp + 65536); \
           stage16(Abase + tid8 + 4096, lp + 65536 + 512); } \
} while (0)

#define ST_B(t_, h_, BUFB_, valid_) do { \
  if (valid_) { \
    const unsigned short* s_ = Bbase + ((size_t)(t_) * 32 + (h_)) * 8192 + tid8; \
    lds_us* d_ = lp + 32768 + (BUFB_) * 16384 + (h_) * 8192 + tid8; \
    stage16(s_, d_); stage16(s_ + 4096, d_ + 4096); \
  } else { stage16(Bbase + tid8, lp + 65536); \
           stage16(Bbase + tid8 + 4096, lp + 65536 + 512); } \
} while (0)

#define MF(MB_, NB_, AF_, BF_) do { \
  _Pragma("unroll") \
  for (int kk_ = 0; kk_ < 2; ++kk_) \
    _Pragma("unroll") \
    for (int mm_ = 0; mm_ < 4; ++mm_) \
      _Pragma("unroll") \
      for (int nn_ = 0; nn_ < 2; ++nn_) \
        acc[(MB_) + mm_][(NB_) + nn_] = __builtin_amdgcn_mfma_f32_16x16x32_bf16( \
            AF_[mm_][kk_], BF_[nn_][kk_], acc[(MB_) + mm_][(NB_) + nn_], 0, 0, 0); \
} while (0)

#define RD_ALO_BLO(dsA_, dsB_) do { \
  aLo[0][0] = dsr<0>(dsA_);      aLo[0][1] = dsr<1024>(dsA_); \
  aLo[1][0] = dsr<2048>(dsA_);   aLo[1][1] = dsr<3072>(dsA_); \
  aLo[2][0] = dsr<4096>(dsA_);   aLo[2][1] = dsr<5120>(dsA_); \
  aLo[3][0] = dsr<6144>(dsA_);   aLo[3][1] = dsr<7168>(dsA_); \
  bLo[0][0] = dsr<0>(dsB_);      bLo[0][1] = dsr<1024>(dsB_); \
  bLo[1][0] = dsr<2048>(dsB_);   bLo[1][1] = dsr<3072>(dsB_); \
} while (0)

// One 4-phase group computing K-tile g from buffer BUF_ (= g&1).
// On entry: aLo,bLo(g) already ISSUED (12 outstanding lgkm ops).
// vmcnt steady state: entry 4 (A(g+1)); +2+2+2+2 staged; vmcnt(4) at ph4
// drains A(g+1)+B(g+1) (tile g+1 published), A(g+2) stays in flight.
#define GROUP(BUF_, tB_, tA_, vB_, vA_, RDN_) do { \
  lds_us* dsA_ = lp + (BUF_) * 16384 + wm * 8192 + lane * 8; \
  lds_us* dsB_ = lp + 32768 + (BUF_) * 16384 + wn * 4096 + lane * 8; \
  lds_us* dsA2_ = lp + ((BUF_) ^ 1) * 16384 + wm * 8192 + lane * 8; \
  lds_us* dsB2_ = lp + 32768 + ((BUF_) ^ 1) * 16384 + wn * 4096 + lane * 8; \
  /* ---- phase 1: Q00 (m0-3, n0-1) ---- */ \
  aHi[0][0] = dsr<8192>(dsA_);   aHi[0][1] = dsr<9216>(dsA_); \
  aHi[1][0] = dsr<10240>(dsA_);  aHi[1][1] = dsr<11264>(dsA_); \
  aHi[2][0] = dsr<12288>(dsA_);  aHi[2][1] = dsr<13312>(dsA_); \
  aHi[3][0] = dsr<14336>(dsA_);  aHi[3][1] = dsr<15360>(dsA_); \
  ST_B(tB_, 0, (BUF_) ^ 1, vB_); \
  BAR(); WAIT_LGKM(8); /* drain aLo,bLo; aHi stays in flight */ \
  __builtin_amdgcn_s_setprio(1); \
  MF(0, 0, aLo, bLo); \
  __builtin_amdgcn_s_setprio(0); \
  BAR(); \
  /* ---- phase 2: Q10 (m4-7, n0-1) ---- */ \
  bHi[0][0] = dsr<4096>(dsB_);   bHi[0][1] = dsr<5120>(dsB_); \
  bHi[1][0] = dsr<6144>(dsB_);   bHi[1][1] = dsr<7168>(dsB_); \
  ST_B(tB_, 1, (BUF_) ^ 1, vB_); \
  BAR(); WAIT_LGKM(4); /* drain aHi; bHi stays in flight */ \
  __builtin_amdgcn_s_setprio(1); \
  MF(4, 0, aHi, bLo); \
  __builtin_amdgcn_s_setprio(0); \
  BAR(); \
  /* ---- phase 3: Q01 (m0-3, n2-3) ---- */ \
  ST_A(tA_, 0, (BUF_), vA_); \
  BAR(); WAIT_LGKM(0); /* drain bHi */ \
  __builtin_amdgcn_s_setprio(1); \
  MF(0, 2, aLo, bHi); \
  __builtin_amdgcn_s_setprio(0); \
  BAR(); \
  /* ---- phase 4: Q11 (m4-7, n2-3) ---- */ \
  ST_A(tA_, 1, (BUF_), vA_); \
  asm volatile("s_waitcnt vmcnt(4)" ::: "memory"); \
  BAR(); \
  if (RDN_) { RD_ALO_BLO(dsA2_, dsB2_); } \
  __builtin_amdgcn_s_setprio(1); \
  MF(4, 2, aHi, bHi); \
  __builtin_amdgcn_s_setprio(0); \
  BAR(); \
} while (0)

__global__ __launch_bounds__(512, 2) void MXFP4_gemm_kernel(
    const unsigned short* __restrict__ A,
    const unsigned short* __restrict__ B,
    const float* __restrict__ bias,
    float* __restrict__ C) {
  __shared__ unsigned short LDS[66560];  // 130 KB
  lds_us* lp = (lds_us*)LDS;

  const int tid  = threadIdx.x;
  const int lane = tid & 63;
  const int wv   = tid >> 6;   // wave 0..7
  const int wm   = wv >> 2;    // 0..1  (M half)
  const int wn   = wv & 3;     // 0..3  (N quarter)
  const int tid8 = tid * 8;

  // 2-D chunk XCD swizzle: XCD x owns an 8tm x 8tn sub-square (bijective).
  const int bid = blockIdx.x;
  const int xcd = bid & 7;
  const int idx = bid >> 3;                 // 0..63 within XCD
  const int tm  = (xcd & 3) * 8 + (idx & 7);   // 0..31
  const int tn  = (xcd >> 2) * 8 + (idx >> 3); // 0..15
  const int brow = tm * 256;
  const int bcol = tn * 256;

  // blocked-layout staging bases (identity copy: 16-KB block per (tile, half))
  const unsigned short* Abase = A + (size_t)(tm * 2) * 8192;
  const unsigned short* Bbase = B + (size_t)(tn * 2) * 8192;

  f32x4 acc[8][4] = {};
  bf16x8 aLo[4][2], aHi[4][2], bLo[2][2], bHi[2][2];

  // ---- prologue: tile 0 (A lo/hi, B lo/hi) + tile 1 A halves ----
  ST_A(0, 0, 0, true); ST_A(0, 1, 0, true);
  ST_B(0, 0, 0, true); ST_B(0, 1, 0, true);
  ST_A(1, 0, 1, true); ST_A(1, 1, 1, true);
  asm volatile("s_waitcnt vmcnt(4)" ::: "memory");  // tile 0 landed; A(1) in flight
  BAR();
  {  // issue aLo,bLo of tile 0 (buffer 0) — drained at first GROUP's ph1
    lds_us* dsA0 = lp + wm * 8192 + lane * 8;
    lds_us* dsB0 = lp + 32768 + wn * 4096 + lane * 8;
    RD_ALO_BLO(dsA0, dsB0);
  }

  // ---- main loop: 31 iters x 2 K-tiles ----
  for (int it = 0; it < 31; ++it) {
    const int g0 = 2 * it;
    GROUP(0, g0 + 1, g0 + 2, true, true, true);
    GROUP(1, g0 + 2, g0 + 3, true, true, true);
  }
  // ---- tail groups 62, 63 (dummy stages keep vmcnt accounting uniform) ----
  GROUP(0, 63, 64, true, false, true);
  GROUP(1, 64, 65, false, false, false);

  // ---- epilogue: C = acc + bias;  frag: col=lane&15, row=(lane>>4)*4+j ----
  const int rb = brow + wm * 128 + (lane >> 4) * 4;
  const int cb = bcol + wn * 64 + (lane & 15);
#pragma unroll
  for (int n = 0; n < 4; ++n) {
    const int col = cb + n * 16;
    const float bv = bias[col];
#pragma unroll
    for (int m = 0; m < 8; ++m) {
      const int row = rb + m * 16;
#pragma unroll
      for (int j = 0; j < 4; ++j)
        C[(size_t)(row + j) * N_DIM + col] = acc[m][n][j] + bv;
    }
  }
}

extern "C" void kernel_launch(void* const* d_in, const int* in_sizes, int n_in,
                              void* d_out, int out_size, void* d_ws, size_t ws_size,
                              hipStream_t stream) {
  const float* x      = (const float*)d_in[0];
  const int*   wq     = (const int*)d_in[1];
  const float* scales = (const float*)d_in[2];
  const float* bias   = (const float*)d_in[3];
  float*       out    = (float*)d_out;

  unsigned short* wb = (unsigned short*)d_ws;                    // 33.5 MB blocked
  unsigned short* xb = wb + (size_t)N_DIM * K_DIM;               // 67 MB blocked

  MXFP4_dequant_kernel<<<(N_DIM * (long)K_DIM / 8) / 256, 256, 0, stream>>>(wq, scales, wb);
  MXFP4_cvt_kernel<<<(M_DIM * (long)K_DIM / 8) / 256, 256, 0, stream>>>(x, xb);

  MXFP4_gemm_kernel<<<512, 512, 0, stream>>>(xb, wb, bias, out);
}